// Round 9
// baseline (202.846 us; speedup 1.0000x reference)
//
#include <hip/hip_runtime.h>

#define HH 192
#define WW 192
#define LL (HH * WW)   // 36864
#define CC 512
#define KK 64
#define EPSF 1e-12f
typedef unsigned long long ull;
typedef unsigned int uint;
typedef unsigned short ushort;

// k3 decomposition
#define NCHUNK 192
#define CHUNKL (LL / NCHUNK)   // 192

typedef short bf16x8 __attribute__((ext_vector_type(8)));
typedef float f32x4 __attribute__((ext_vector_type(4)));

// ---------------------------------------------------------------- async global->LDS, 16B per lane
__device__ __forceinline__ void gl16(const void* g, void* l) {
    __builtin_amdgcn_global_load_lds((const __attribute__((address_space(1))) void*)g,
                                     (__attribute__((address_space(3))) void*)l, 16, 0, 0);
}

// ---------------------------------------------------------------- fp32 -> 3-way bf16 split (hi/mid/lo, truncation; exact residuals)
__device__ inline void split3(float v, ushort& h, ushort& md, ushort& lo) {
    uint b  = __float_as_uint(v);
    uint hb = b & 0xFFFF0000u;
    float r1 = v - __uint_as_float(hb);          // exact
    uint mb = __float_as_uint(r1) & 0xFFFF0000u;
    float r2 = r1 - __uint_as_float(mb);         // exact
    uint lb = __float_as_uint(r2) & 0xFFFF0000u;
    h = (ushort)(hb >> 16); md = (ushort)(mb >> 16); lo = (ushort)(lb >> 16);
}

// ---------------------------------------------------------------- fp32 -> 2-way bf16 split (hi + residual lo)
__device__ inline void split2(float v, ushort& h, ushort& lo) {
    uint b  = __float_as_uint(v);
    uint hb = b & 0xFFFF0000u;
    float r = v - __uint_as_float(hb);           // exact
    h = (ushort)(hb >> 16); lo = (ushort)(__float_as_uint(r) >> 16);
}

// ---------------------------------------------------------------- k0: pre-split conv_w into fragment-ordered bf16 hi/mid/lo arrays.
// Fragment order: element W[kg*16+m][s*32 + quad*8 + j] -> ushort index ((s*4+kg)*64 + quad*16 + m)*8 + j
// so the W-slice for step s, kg is a contiguous 1KB block (64 lanes x 16B) -> one gl16.
__global__ __launch_bounds__(256) void k0_prep(const float* __restrict__ w,
                                               ushort* __restrict__ Whi,
                                               ushort* __restrict__ Wmid,
                                               ushort* __restrict__ Wlo,
                                               float* __restrict__ Szero) {
    int idx = blockIdx.x * 256 + threadIdx.x;   // 32768 = KK*CC
    int k = idx >> 9;
    int c = idx & 511;
    int s = c >> 5, w32 = c & 31, quad = w32 >> 3, j = w32 & 7;
    int kg = k >> 4, m = k & 15;
    int dst = (((s * 4 + kg) * 4 + quad) * 16 + m) * 8 + j;
    float v = w[idx];
    ushort h, md, lo;
    split3(v, h, md, lo);
    Whi[dst] = h; Wmid[dst] = md; Wlo[dst] = lo;
    if (blockIdx.x == 0 && threadIdx.x < 128) Szero[threadIdx.x] = 0.f;  // S[64]+rowsq[64]
}

// ---------------------------------------------------------------- k1: MFMA logits GEMM + fused norm/softmax/top2.
// v7: R7 structure (m97 recipe: both operands gl16-staged, ds_read frags, dbuf, 1 barrier/step)
// with SMALLER BARRIER DOMAINS for block-level TLP. R7 had 576 blocks (2.25/CU): when a block
// hit its per-step vmcnt drain, the CU had no other block to fill the memory pipe.
// Now: 1152 blocks x 128 thr (2 waves), 32 px/block, 32KB LDS -> 4.5 blocks/CU co-resident
// (LDS allows 5); ~4.5 independent barrier groups per CU overlap drain with compute.
// Per-wave work unchanged: 16 px, full c=512, 16 steps. W L2 re-read doubles (216MB, L2-hit,
// overlapped). 6-term triple-bf16 MFMA => ~2^-24 rel err => top-2 SET selection stable.
__global__ __launch_bounds__(128) void k1_logits(const float* __restrict__ x,
                                                 const ushort* __restrict__ Whi,
                                                 const ushort* __restrict__ Wmid,
                                                 const ushort* __restrict__ Wlo,
                                                 float* __restrict__ soft,
                                                 float* __restrict__ invn,
                                                 ull* __restrict__ keep) {
    __shared__ ushort wl[2][12][512];   // 24 KB: W chunks [buf][plane*4+kg][lane*8]
    __shared__ float xs[2][32][32];     // 8 KB: x tile [buf][c-row][px]
    int t = threadIdx.x, lane = t & 63, wid = t >> 6;   // wid 0..1 = px-group
    int m = lane & 15, quad = lane >> 4;
    int pb = blockIdx.x * 32;

    f32x4 acc[4];
#pragma unroll
    for (int kg = 0; kg < 4; ++kg) acc[kg] = (f32x4){0.f, 0.f, 0.f, 0.f};
    float ss = 0.f;

    const ushort* Wp[3] = {Whi, Wmid, Wlo};
    // x staging: one gl16 = 8 rows x 128B; wave w covers rows [16w+8j, +8), j=0,1.
    // lane: row = 16w + 8j + (lane>>3), col 16B-granule = lane&7.
    const float* gxbase = x + (size_t)(16 * wid + (lane >> 3)) * LL + pb + (lane & 7) * 4;

    // ---- prologue: stage step 0 into buf 0 ----
#pragma unroll
    for (int j = 0; j < 2; ++j)
        gl16(gxbase + (size_t)(8 * j) * LL, &xs[0][16 * wid + 8 * j][0]);
#pragma unroll
    for (int q = 0; q < 6; ++q) {
        int ch = 6 * wid + q;                  // 0..11: plane = ch>>2, kg = ch&3
        gl16(Wp[ch >> 2] + (size_t)(((0 * 4 + (ch & 3)) * 64 + lane) * 8), &wl[0][ch][(size_t)lane * 8]);
    }

    int cur = 0;
#pragma unroll
    for (int s = 0; s < 16; ++s) {
        __syncthreads();   // drains vmcnt: buf[cur] staged; prev reads of buf[cur^1] done
        if (s < 15) {
#pragma unroll
            for (int j = 0; j < 2; ++j)
                gl16(gxbase + (size_t)((s + 1) * 32 + 8 * j) * LL, &xs[cur ^ 1][16 * wid + 8 * j][0]);
#pragma unroll
            for (int q = 0; q < 6; ++q) {
                int ch = 6 * wid + q;
                gl16(Wp[ch >> 2] + (size_t)((((s + 1) * 4 + (ch & 3)) * 64 + lane) * 8),
                     &wl[cur ^ 1][ch][(size_t)lane * 8]);
            }
        }
        // ---- B frag from LDS: lane (m,quad) reads x[quad*8+j][wid*16+m] ----
        float xv[8];
#pragma unroll
        for (int j = 0; j < 8; ++j) xv[j] = xs[cur][quad * 8 + j][wid * 16 + m];
        bf16x8 Bh, Bm, Bl;
#pragma unroll
        for (int j = 0; j < 8; ++j) {
            float v = xv[j];
            ss = fmaf(v, v, ss);
            ushort h, md, lo;
            split3(v, h, md, lo);
            Bh[j] = (short)h; Bm[j] = (short)md; Bl[j] = (short)lo;
        }
        // ---- per kg: 3 ds_read_b128 A-frags + 6-term MFMA (<=3 A-frags live) ----
#pragma unroll
        for (int kg = 0; kg < 4; ++kg) {
            bf16x8 Ah = *(const bf16x8*)&wl[cur][kg    ][(size_t)lane * 8];
            bf16x8 Am = *(const bf16x8*)&wl[cur][4 + kg][(size_t)lane * 8];
            bf16x8 Al = *(const bf16x8*)&wl[cur][8 + kg][(size_t)lane * 8];
            f32x4 a = acc[kg];
            a = __builtin_amdgcn_mfma_f32_16x16x32_bf16(Ah, Bh, a, 0, 0, 0);
            a = __builtin_amdgcn_mfma_f32_16x16x32_bf16(Ah, Bm, a, 0, 0, 0);
            a = __builtin_amdgcn_mfma_f32_16x16x32_bf16(Am, Bh, a, 0, 0, 0);
            a = __builtin_amdgcn_mfma_f32_16x16x32_bf16(Ah, Bl, a, 0, 0, 0);
            a = __builtin_amdgcn_mfma_f32_16x16x32_bf16(Al, Bh, a, 0, 0, 0);
            a = __builtin_amdgcn_mfma_f32_16x16x32_bf16(Am, Bm, a, 0, 0, 0);
            acc[kg] = a;
        }
        cur ^= 1;
    }

    // ---- epilogue: wave-local (each wave owns its 16 px, full c contracted) ----
    ss += __shfl_xor(ss, 16);
    ss += __shfl_xor(ss, 32);
    float iv = 1.0f / fmaxf(sqrtf(ss), EPSF);
    int px = pb + wid * 16 + m;
    if (quad == 0) invn[px] = iv;

    float lg[16];
    float M1 = -3.0e38f, M2 = -3.0e38f; int I1 = 0, I2 = 0;
#pragma unroll
    for (int kg = 0; kg < 4; ++kg)
#pragma unroll
        for (int r = 0; r < 4; ++r) {
            float v = acc[kg][r] * iv;
            lg[kg * 4 + r] = v;
            int kk = kg * 16 + quad * 4 + r;
            if (v > M1)      { M2 = M1; I2 = I1; M1 = v; I1 = kk; }
            else if (v > M2) { M2 = v; I2 = kk; }
        }
    // cross-quad butterfly merge of (top1, top2), ties -> lower index
#pragma unroll
    for (int st = 0; st < 2; ++st) {
        int d = 16 << st;
        float a1 = __shfl_xor(M1, d); int b1 = __shfl_xor(I1, d);
        float a2 = __shfl_xor(M2, d); int b2 = __shfl_xor(I2, d);
        if (a1 > M1 || (a1 == M1 && b1 < I1)) { M2 = M1; I2 = I1; M1 = a1; I1 = b1; }
        else if (a1 > M2 || (a1 == M2 && b1 < I2)) { M2 = a1; I2 = b1; }
        if (a2 > M1 || (a2 == M1 && b2 < I1)) { M2 = M1; I2 = I1; M1 = a2; I1 = b2; }
        else if (a2 > M2 || (a2 == M2 && b2 < I2)) { M2 = a2; I2 = b2; }
    }

    float es = 0.f;
#pragma unroll
    for (int q = 0; q < 16; ++q) { float e = __expf(lg[q] - M1); lg[q] = e; es += e; }
    es += __shfl_xor(es, 16);
    es += __shfl_xor(es, 32);
    float rs = 1.0f / es;

    float4* sp = (float4*)(soft + (size_t)px * KK + quad * 4);
#pragma unroll
    for (int kg = 0; kg < 4; ++kg) {
        float4 o;
        o.x = lg[kg * 4 + 0] * rs; o.y = lg[kg * 4 + 1] * rs;
        o.z = lg[kg * 4 + 2] * rs; o.w = lg[kg * 4 + 3] * rs;
        sp[kg * 4] = o;     // soft[px*64 + kg*16 + quad*4 .. +3]
    }
    if (quad == 0) keep[px] = (1ull << I1) | (1ull << I2);
}

// ---------------------------------------------------------------- k2: weight = soft*cnt*border^4*invn[l]; S[k] += unscaled.
// Emits w2^T pre-split hi/lo bf16 planes in k3's A-fragment order; one 16B store per plane.
__global__ __launch_bounds__(256) void k2_weight(const float* __restrict__ soft,
                                                 const ull* __restrict__ keep,
                                                 const float* __restrict__ invn,
                                                 float* __restrict__ S,
                                                 ushort* __restrict__ w2t_hi,
                                                 ushort* __restrict__ w2t_lo) {
    __shared__ float sred[4][64];
    int t = threadIdx.x, lane = t & 63, wid = t >> 6;
    int l0 = blockIdx.x * 32 + wid * 8;
    float sk = 0.f;
    bf16x8 hv, lv;
#pragma unroll
    for (int p = 0; p < 8; ++p) {
        int l = l0 + p;                           // wave-uniform
        int i = l / WW, j = l % WW;
        int m = min(min(i, HH - 1 - i), min(j, WW - 1 - j));
        float bm = (float)m; bm *= bm; bm *= bm;  // m^4
        int cnt = 0;
#pragma unroll
        for (int di = -1; di <= 1; ++di) {
            int ii = i + di;
            if (ii < 0 || ii >= HH) continue;
#pragma unroll
            for (int dj = -1; dj <= 1; ++dj) {
                int jj = j + dj;
                if (jj < 0 || jj >= WW) continue;
                ull nb = keep[ii * WW + jj];      // uniform -> s_load
                cnt += (int)((nb >> lane) & 1ull);
            }
        }
        float v = soft[(size_t)l * KK + lane];    // coalesced 256B
        float u = v * (float)cnt * bm;            // unscaled weight
        sk += u;
        float w2v = u * invn[l];
        ushort h, lo;
        split2(w2v, h, lo);
        hv[p] = (short)h; lv[p] = (short)lo;
    }
    size_t off = (size_t)((((l0 >> 5) * 4 + (lane >> 4)) * 64 + ((l0 >> 3) & 3) * 16 + (lane & 15)) * 8);
    *(bf16x8*)(w2t_hi + off) = hv;
    *(bf16x8*)(w2t_lo + off) = lv;
    sred[wid][lane] = sk;
    __syncthreads();
    if (wid == 0)
        atomicAdd(&S[lane], sred[0][lane] + sred[1][lane] + sred[2][lane] + sred[3][lane]);
}

// ---------------------------------------------------------------- k3: MFMA GEMM, m97 recipe (round-8, neutral-verified; kept).
// partials[ch][k][c] = sum_{l in chunk} w2[l][k] * x[c][l]
__global__ __launch_bounds__(256) void k3_mfma(const ushort* __restrict__ w2t_hi,
                                               const ushort* __restrict__ w2t_lo,
                                               const float* __restrict__ x,
                                               float* __restrict__ partials) {
    __shared__ ushort wa[2][8][512];    // 16 KB: A chunks [buf][plane*4+kg][lane*8]
    __shared__ float  xb[2][128][32];   // 32 KB: B tile [buf][c][l] (source-swizzled)
    int chunk = blockIdx.x;             // 0..191
    int c0 = blockIdx.y * 128;          // 0..3
    int l0 = chunk * CHUNKL;
    int lsbase = chunk * (CHUNKL / 32); // first 32-l step index
    int t = threadIdx.x, lane = t & 63, wid = t >> 6;
    int m = lane & 15, quad = lane >> 4;

    f32x4 acc[4][2];
#pragma unroll
    for (int kg = 0; kg < 4; ++kg)
#pragma unroll
        for (int cg = 0; cg < 2; ++cg) acc[kg][cg] = (f32x4){0.f, 0.f, 0.f, 0.f};

    // B staging geometry: lane rowg = lane>>3, phys granule g = lane&7; source l-granule = g^rowg.
    int rowg = lane >> 3, gph = lane & 7;
    int swzl = ((gph ^ rowg) * 4);

    // ---- prologue: stage step 0 into buf 0 ----
#pragma unroll
    for (int q = 0; q < 2; ++q) {
        int ch = 2 * wid + q;          // 0..7: plane = ch>>2, kg = ch&3
        const ushort* src = (ch < 4 ? w2t_hi : w2t_lo) + (size_t)(((lsbase * 4 + (ch & 3)) * 64 + lane) * 8);
        gl16(src, &wa[0][ch][(size_t)lane * 8]);
    }
#pragma unroll
    for (int i = 0; i < 4; ++i) {
        int row = wid * 32 + 8 * i + rowg;
        gl16(x + (size_t)(c0 + row) * LL + l0 + swzl, &xb[0][wid * 32 + 8 * i][0]);
    }

    int cur = 0;
#pragma unroll
    for (int st = 0; st < CHUNKL / 32; ++st) {
        __syncthreads();   // drains vmcnt: buf[cur] staged; prev reads of buf[cur^1] done
        if (st < CHUNKL / 32 - 1) {
#pragma unroll
            for (int q = 0; q < 2; ++q) {
                int ch = 2 * wid + q;
                const ushort* src = (ch < 4 ? w2t_hi : w2t_lo) +
                                    (size_t)((((lsbase + st + 1) * 4 + (ch & 3)) * 64 + lane) * 8);
                gl16(src, &wa[cur ^ 1][ch][(size_t)lane * 8]);
            }
#pragma unroll
            for (int i = 0; i < 4; ++i) {
                int row = wid * 32 + 8 * i + rowg;
                gl16(x + (size_t)(c0 + row) * LL + l0 + (st + 1) * 32 + swzl,
                     &xb[cur ^ 1][wid * 32 + 8 * i][0]);
            }
        }
        // ---- A frags: 8 ds_read_b128, conflict-free (2 lanes/bank) ----
        bf16x8 Ah[4], Al[4];
#pragma unroll
        for (int kg = 0; kg < 4; ++kg) {
            Ah[kg] = *(const bf16x8*)&wa[cur][kg    ][(size_t)lane * 8];
            Al[kg] = *(const bf16x8*)&wa[cur][4 + kg][(size_t)lane * 8];
        }
        // ---- B frags: 2x ds_read_b128 per cg at swizzled granules + in-register split ----
        bf16x8 Bh[2], Bl[2];
#pragma unroll
        for (int cg = 0; cg < 2; ++cg) {
            int crow = wid * 32 + cg * 16 + m;
            const float* xr = &xb[cur][crow][0];
            float4 v0 = *(const float4*)(xr + (((quad * 2    ) ^ (m & 7)) * 4));
            float4 v1 = *(const float4*)(xr + (((quad * 2 + 1) ^ (m & 7)) * 4));
            float vv[8] = {v0.x, v0.y, v0.z, v0.w, v1.x, v1.y, v1.z, v1.w};
#pragma unroll
            for (int j = 0; j < 8; ++j) {
                ushort h, lo;
                split2(vv[j], h, lo);
                Bh[cg][j] = (short)h; Bl[cg][j] = (short)lo;
            }
        }
        // ---- 3-term MFMA ----
#pragma unroll
        for (int cg = 0; cg < 2; ++cg)
#pragma unroll
            for (int kg = 0; kg < 4; ++kg) {
                acc[kg][cg] = __builtin_amdgcn_mfma_f32_16x16x32_bf16(Ah[kg], Bh[cg], acc[kg][cg], 0, 0, 0);
                acc[kg][cg] = __builtin_amdgcn_mfma_f32_16x16x32_bf16(Ah[kg], Bl[cg], acc[kg][cg], 0, 0, 0);
                acc[kg][cg] = __builtin_amdgcn_mfma_f32_16x16x32_bf16(Al[kg], Bh[cg], acc[kg][cg], 0, 0, 0);
            }
        cur ^= 1;
    }
    // ---- store: D row = kg*16 + quad*4 + r, col = c0 + wid*32 + cg*16 + m ----
    float* pp = partials + (size_t)chunk * KK * CC;
#pragma unroll
    for (int kg = 0; kg < 4; ++kg)
#pragma unroll
        for (int cg = 0; cg < 2; ++cg) {
            int cout = c0 + wid * 32 + cg * 16 + m;
#pragma unroll
            for (int r = 0; r < 4; ++r) {
                int kout = kg * 16 + quad * 4 + r;
                pp[(size_t)kout * CC + cout] = acc[kg][cg][r];
            }
        }
}

// ---------------------------------------------------------------- k4a: reduce partials -> vlad, rowsq atomic
__global__ __launch_bounds__(512) void k4a_reduce(const float* __restrict__ partials,
                                                  const float* __restrict__ S,
                                                  const float* __restrict__ cent,
                                                  float* __restrict__ vlad,
                                                  float* __restrict__ rowsq) {
    __shared__ float red[512];
    int k = blockIdx.x;
    int ci = threadIdx.x & 127;
    int c = blockIdx.y * 128 + ci;
    int q = threadIdx.x >> 7;                       // 0..3
    const float* pk = partials + (size_t)q * (NCHUNK / 4) * KK * CC + (size_t)k * CC + c;
    float s0 = 0.f, s1 = 0.f, s2 = 0.f, s3 = 0.f;
    for (int ch = 0; ch < NCHUNK / 4; ch += 4) {
        s0 += pk[(size_t)(ch + 0) * KK * CC];
        s1 += pk[(size_t)(ch + 1) * KK * CC];
        s2 += pk[(size_t)(ch + 2) * KK * CC];
        s3 += pk[(size_t)(ch + 3) * KK * CC];
    }
    red[threadIdx.x] = (s0 + s1) + (s2 + s3);
    __syncthreads();
    float vsq = 0.f;
    if (q == 0) {
        float v = red[ci] + red[ci + 128] + red[ci + 256] + red[ci + 384];
        v -= S[k] * cent[k * CC + c];
        vlad[k * CC + c] = v;
        vsq = v * v;
    }
    __syncthreads();
    red[threadIdx.x] = vsq;
    __syncthreads();
    for (int off = 256; off > 0; off >>= 1) {
        if (threadIdx.x < off) red[threadIdx.x] += red[threadIdx.x + off];
        __syncthreads();
    }
    if (threadIdx.x == 0) atomicAdd(&rowsq[k], red[0]);
}

// ---------------------------------------------------------------- k4c: out = vlad * rn[k], rn computed inline from rowsq
__global__ __launch_bounds__(256) void k4c_finish(const float* __restrict__ vlad,
                                                  const float* __restrict__ rowsq,
                                                  float* __restrict__ out) {
    __shared__ float rns[64];
    int t = threadIdx.x;
    if (t < 64) {
        float tot = rowsq[t];
        float r = 1.0f / fmaxf(sqrtf(tot), EPSF);
        float contrib = tot * r * r;
#pragma unroll
        for (int off = 32; off; off >>= 1) contrib += __shfl_xor(contrib, off, 64);
        float ginv = 1.0f / fmaxf(sqrtf(contrib), EPSF);
        rns[t] = r * ginv;
    }
    __syncthreads();
    int idx4 = blockIdx.x * 256 + t;               // 8192 float4s
    int k = idx4 >> 7;
    float s = rns[k];
    float4 v = ((const float4*)vlad)[idx4];
    v.x *= s; v.y *= s; v.z *= s; v.w *= s;
    ((float4*)out)[idx4] = v;
}

// ----------------------------------------------------------------
extern "C" void kernel_launch(void* const* d_in, const int* in_sizes, int n_in,
                              void* d_out, int out_size, void* d_ws, size_t ws_size,
                              hipStream_t stream) {
    const float* x      = (const float*)d_in[0];   // (512,192,192)
    const float* conv_w = (const float*)d_in[1];   // (64,512)
    const float* cent   = (const float*)d_in[2];   // (64,512)
    float* out = (float*)d_out;                    // 32768 fp32

    float* ws    = (float*)d_ws;
    ushort* Whi  = (ushort*)ws;                     // 32768 ushorts (fragment-ordered)
    ushort* Wmid = Whi + 32768;
    ushort* Wlo  = Wmid + 32768;                    // 3 x 64KB = 49152 floats total
    float* soft  = ws + 49152;                      // KK*LL
    float* invn  = soft + (size_t)KK * LL;          // 36864
    float* S     = invn + LL;                       // 64
    float* rowsq = S + KK;                          // 64  (S..rowsq contiguous 128 floats)
    float* vlad  = rowsq + KK;                      // 32768
    ull*   keep  = (ull*)(vlad + 32768);            // LL u64
    ushort* w2t_hi = (ushort*)(keep + LL);          // LL*KK ushorts (4.7 MB), fragment-ordered
    ushort* w2t_lo = w2t_hi + (size_t)LL * KK;      // LL*KK ushorts
    float* partials = (float*)(w2t_lo + (size_t)LL * KK);  // NCHUNK*KK*CC floats (25.2 MB)

    k0_prep<<<(KK * CC) / 256, 256, 0, stream>>>(conv_w, Whi, Wmid, Wlo, S);
    k1_logits<<<LL / 32, 128, 0, stream>>>(x, Whi, Wmid, Wlo, soft, invn, keep);
    k2_weight<<<LL / 32, 256, 0, stream>>>(soft, keep, invn, S, w2t_hi, w2t_lo);
    k3_mfma<<<dim3(NCHUNK, 4), 256, 0, stream>>>(w2t_hi, w2t_lo, x, partials);
    k4a_reduce<<<dim3(KK, 4), 512, 0, stream>>>(partials, S, cent, vlad, rowsq);
    k4c_finish<<<(KK * CC / 4) / 256, 256, 0, stream>>>(vlad, rowsq, out);
}

// Round 10
// 196.030 us; speedup vs baseline: 1.0348x; 1.0348x over previous
//
#include <hip/hip_runtime.h>

#define HH 192
#define WW 192
#define LL (HH * WW)   // 36864
#define CC 512
#define KK 64
#define EPSF 1e-12f
typedef unsigned long long ull;
typedef unsigned int uint;
typedef unsigned short ushort;

// k3 decomposition
#define NCHUNK 192
#define CHUNKL (LL / NCHUNK)   // 192

typedef short bf16x8 __attribute__((ext_vector_type(8)));
typedef float f32x4 __attribute__((ext_vector_type(4)));

// ---------------------------------------------------------------- async global->LDS, 16B per lane
__device__ __forceinline__ void gl16(const void* g, void* l) {
    __builtin_amdgcn_global_load_lds((const __attribute__((address_space(1))) void*)g,
                                     (__attribute__((address_space(3))) void*)l, 16, 0, 0);
}

// ---------------------------------------------------------------- fp32 -> 3-way bf16 split (hi/mid/lo, truncation; exact residuals)
__device__ inline void split3(float v, ushort& h, ushort& md, ushort& lo) {
    uint b  = __float_as_uint(v);
    uint hb = b & 0xFFFF0000u;
    float r1 = v - __uint_as_float(hb);          // exact
    uint mb = __float_as_uint(r1) & 0xFFFF0000u;
    float r2 = r1 - __uint_as_float(mb);         // exact
    uint lb = __float_as_uint(r2) & 0xFFFF0000u;
    h = (ushort)(hb >> 16); md = (ushort)(mb >> 16); lo = (ushort)(lb >> 16);
}

// ---------------------------------------------------------------- fp32 -> 2-way bf16 split (hi + residual lo)
__device__ inline void split2(float v, ushort& h, ushort& lo) {
    uint b  = __float_as_uint(v);
    uint hb = b & 0xFFFF0000u;
    float r = v - __uint_as_float(hb);           // exact
    h = (ushort)(hb >> 16); lo = (ushort)(__float_as_uint(r) >> 16);
}

// ---------------------------------------------------------------- k0: pre-split conv_w into fragment-ordered bf16 hi/mid/lo arrays.
__global__ __launch_bounds__(256) void k0_prep(const float* __restrict__ w,
                                               ushort* __restrict__ Whi,
                                               ushort* __restrict__ Wmid,
                                               ushort* __restrict__ Wlo,
                                               float* __restrict__ Szero) {
    int idx = blockIdx.x * 256 + threadIdx.x;   // 32768 = KK*CC
    int k = idx >> 9;
    int c = idx & 511;
    int s = c >> 5, w32 = c & 31, quad = w32 >> 3, j = w32 & 7;
    int kg = k >> 4, m = k & 15;
    int dst = (((s * 4 + kg) * 4 + quad) * 16 + m) * 8 + j;
    float v = w[idx];
    ushort h, md, lo;
    split3(v, h, md, lo);
    Whi[dst] = h; Wmid[dst] = md; Wlo[dst] = lo;
    if (blockIdx.x == 0 && threadIdx.x < 128) Szero[threadIdx.x] = 0.f;  // S[64]+rowsq[64]
}

// ---------------------------------------------------------------- k1: MFMA logits GEMM + fused norm/softmax/top2.
// v8: R7 structure (4 waves, 64 px/block, 576 blocks, m97 staging) + T3/T4 counted-vmcnt
// pipeline. R7's __syncthreads drained vmcnt(0) every step -> full x HBM latency exposed
// 16x/block (k1 stuck at ~31us, MfmaUtil 11%). Now: TRIPLE-buffered LDS (60KB -> 2 blocks/CU);
// batch(s+1) issued at TOP of step s; s_waitcnt vmcnt(5) waits only batch(s) (new batch stays
// in flight across the barrier); raw s_barrier (no auto-drain). Race-free with one barrier:
// batch(s+1) overwrites buf[(s+1)%3], last read at step s-2, and every wave finishes
// compute(s-2) before barrier(s-1) in program order. Compute phase has ZERO vmem ops, so
// vmcnt bookkeeping is exact (5 gl16/batch/wave: 2 x + 3 W).
// 6-term triple-bf16 MFMA => ~2^-24 rel err => top-2 SET selection stable.
__global__ __launch_bounds__(256) void k1_logits(const float* __restrict__ x,
                                                 const ushort* __restrict__ Whi,
                                                 const ushort* __restrict__ Wmid,
                                                 const ushort* __restrict__ Wlo,
                                                 float* __restrict__ soft,
                                                 float* __restrict__ invn,
                                                 ull* __restrict__ keep) {
    __shared__ ushort wl[3][12][512];   // 36 KB: W chunks [buf][plane*4+kg][lane*8]
    __shared__ float xs[3][32][64];     // 24 KB: x tile [buf][c-row][px]
    int t = threadIdx.x, lane = t & 63, wid = t >> 6;   // wid 0..3 = px-group
    int m = lane & 15, quad = lane >> 4;
    int pb = blockIdx.x * 64;

    f32x4 acc[4];
#pragma unroll
    for (int kg = 0; kg < 4; ++kg) acc[kg] = (f32x4){0.f, 0.f, 0.f, 0.f};
    float ss = 0.f;

    const ushort* Wp[3] = {Whi, Wmid, Wlo};
    // wave w stages x rows [4w,4w+4) and [16+4w,16+4w+4) of the 32-row step tile
    const float* gbase = x + (size_t)(4 * wid + quad) * LL + pb + m * 4;

    // ---- prologue: issue batch(0) into buf 0 ----
    gl16(gbase, &xs[0][4 * wid][0]);
    gl16(gbase + (size_t)16 * LL, &xs[0][16 + 4 * wid][0]);
#pragma unroll
    for (int q = 0; q < 3; ++q) {
        int ch = 3 * wid + q;                  // 0..11: plane = ch>>2, kg = ch&3
        gl16(Wp[ch >> 2] + (size_t)(((0 * 4 + (ch & 3)) * 64 + lane) * 8), &wl[0][ch][(size_t)lane * 8]);
    }

#pragma unroll
    for (int s = 0; s < 16; ++s) {
        const int cb = s % 3;
        if (s < 15) {
            const int nb = (s + 1) % 3;
            const float* g = gbase + (size_t)(s + 1) * 32 * LL;
            gl16(g, &xs[nb][4 * wid][0]);
            gl16(g + (size_t)16 * LL, &xs[nb][16 + 4 * wid][0]);
#pragma unroll
            for (int q = 0; q < 3; ++q) {
                int ch = 3 * wid + q;
                gl16(Wp[ch >> 2] + (size_t)((((s + 1) * 4 + (ch & 3)) * 64 + lane) * 8),
                     &wl[nb][ch][(size_t)lane * 8]);
            }
            __builtin_amdgcn_sched_barrier(0);
            asm volatile("s_waitcnt vmcnt(5)" ::: "memory");   // batch(s) landed; batch(s+1) in flight
        } else {
            __builtin_amdgcn_sched_barrier(0);
            asm volatile("s_waitcnt vmcnt(0)" ::: "memory");   // last batch
        }
        __builtin_amdgcn_sched_barrier(0);
        __builtin_amdgcn_s_barrier();                          // raw barrier: no vmcnt auto-drain

        // ---- B frag from LDS: lane (m,quad) reads x[quad*8+j][wid*16+m] ----
        float xv[8];
#pragma unroll
        for (int j = 0; j < 8; ++j) xv[j] = xs[cb][quad * 8 + j][wid * 16 + m];
        bf16x8 Bh, Bm, Bl;
#pragma unroll
        for (int j = 0; j < 8; ++j) {
            float v = xv[j];
            ss = fmaf(v, v, ss);
            ushort h, md, lo;
            split3(v, h, md, lo);
            Bh[j] = (short)h; Bm[j] = (short)md; Bl[j] = (short)lo;
        }
        // ---- per kg: 3 ds_read_b128 A-frags + 6-term MFMA (<=3 A-frags live) ----
#pragma unroll
        for (int kg = 0; kg < 4; ++kg) {
            bf16x8 Ah = *(const bf16x8*)&wl[cb][kg    ][(size_t)lane * 8];
            bf16x8 Am = *(const bf16x8*)&wl[cb][4 + kg][(size_t)lane * 8];
            bf16x8 Al = *(const bf16x8*)&wl[cb][8 + kg][(size_t)lane * 8];
            f32x4 a = acc[kg];
            a = __builtin_amdgcn_mfma_f32_16x16x32_bf16(Ah, Bh, a, 0, 0, 0);
            a = __builtin_amdgcn_mfma_f32_16x16x32_bf16(Ah, Bm, a, 0, 0, 0);
            a = __builtin_amdgcn_mfma_f32_16x16x32_bf16(Am, Bh, a, 0, 0, 0);
            a = __builtin_amdgcn_mfma_f32_16x16x32_bf16(Ah, Bl, a, 0, 0, 0);
            a = __builtin_amdgcn_mfma_f32_16x16x32_bf16(Al, Bh, a, 0, 0, 0);
            a = __builtin_amdgcn_mfma_f32_16x16x32_bf16(Am, Bm, a, 0, 0, 0);
            acc[kg] = a;
        }
    }

    // ---- epilogue: wave-local (each wave owns its 16 px, full c contracted) ----
    ss += __shfl_xor(ss, 16);
    ss += __shfl_xor(ss, 32);
    float iv = 1.0f / fmaxf(sqrtf(ss), EPSF);
    int px = pb + wid * 16 + m;
    if (quad == 0) invn[px] = iv;

    float lg[16];
    float M1 = -3.0e38f, M2 = -3.0e38f; int I1 = 0, I2 = 0;
#pragma unroll
    for (int kg = 0; kg < 4; ++kg)
#pragma unroll
        for (int r = 0; r < 4; ++r) {
            float v = acc[kg][r] * iv;
            lg[kg * 4 + r] = v;
            int kk = kg * 16 + quad * 4 + r;
            if (v > M1)      { M2 = M1; I2 = I1; M1 = v; I1 = kk; }
            else if (v > M2) { M2 = v; I2 = kk; }
        }
    // cross-quad butterfly merge of (top1, top2), ties -> lower index
#pragma unroll
    for (int st = 0; st < 2; ++st) {
        int d = 16 << st;
        float a1 = __shfl_xor(M1, d); int b1 = __shfl_xor(I1, d);
        float a2 = __shfl_xor(M2, d); int b2 = __shfl_xor(I2, d);
        if (a1 > M1 || (a1 == M1 && b1 < I1)) { M2 = M1; I2 = I1; M1 = a1; I1 = b1; }
        else if (a1 > M2 || (a1 == M2 && b1 < I2)) { M2 = a1; I2 = b1; }
        if (a2 > M1 || (a2 == M1 && b2 < I1)) { M2 = M1; I2 = I1; M1 = a2; I1 = b2; }
        else if (a2 > M2 || (a2 == M2 && b2 < I2)) { M2 = a2; I2 = b2; }
    }

    float es = 0.f;
#pragma unroll
    for (int q = 0; q < 16; ++q) { float e = __expf(lg[q] - M1); lg[q] = e; es += e; }
    es += __shfl_xor(es, 16);
    es += __shfl_xor(es, 32);
    float rs = 1.0f / es;

    float4* sp = (float4*)(soft + (size_t)px * KK + quad * 4);
#pragma unroll
    for (int kg = 0; kg < 4; ++kg) {
        float4 o;
        o.x = lg[kg * 4 + 0] * rs; o.y = lg[kg * 4 + 1] * rs;
        o.z = lg[kg * 4 + 2] * rs; o.w = lg[kg * 4 + 3] * rs;
        sp[kg * 4] = o;     // soft[px*64 + kg*16 + quad*4 .. +3]
    }
    if (quad == 0) keep[px] = (1ull << I1) | (1ull << I2);
}

// ---------------------------------------------------------------- k2: weight = soft*cnt*border^4*invn[l]; S[k] += unscaled.
// Emits w2^T pre-split hi/lo bf16 planes in k3's A-fragment order; one 16B store per plane.
__global__ __launch_bounds__(256) void k2_weight(const float* __restrict__ soft,
                                                 const ull* __restrict__ keep,
                                                 const float* __restrict__ invn,
                                                 float* __restrict__ S,
                                                 ushort* __restrict__ w2t_hi,
                                                 ushort* __restrict__ w2t_lo) {
    __shared__ float sred[4][64];
    int t = threadIdx.x, lane = t & 63, wid = t >> 6;
    int l0 = blockIdx.x * 32 + wid * 8;
    float sk = 0.f;
    bf16x8 hv, lv;
#pragma unroll
    for (int p = 0; p < 8; ++p) {
        int l = l0 + p;                           // wave-uniform
        int i = l / WW, j = l % WW;
        int m = min(min(i, HH - 1 - i), min(j, WW - 1 - j));
        float bm = (float)m; bm *= bm; bm *= bm;  // m^4
        int cnt = 0;
#pragma unroll
        for (int di = -1; di <= 1; ++di) {
            int ii = i + di;
            if (ii < 0 || ii >= HH) continue;
#pragma unroll
            for (int dj = -1; dj <= 1; ++dj) {
                int jj = j + dj;
                if (jj < 0 || jj >= WW) continue;
                ull nb = keep[ii * WW + jj];      // uniform -> s_load
                cnt += (int)((nb >> lane) & 1ull);
            }
        }
        float v = soft[(size_t)l * KK + lane];    // coalesced 256B
        float u = v * (float)cnt * bm;            // unscaled weight
        sk += u;
        float w2v = u * invn[l];
        ushort h, lo;
        split2(w2v, h, lo);
        hv[p] = (short)h; lv[p] = (short)lo;
    }
    size_t off = (size_t)((((l0 >> 5) * 4 + (lane >> 4)) * 64 + ((l0 >> 3) & 3) * 16 + (lane & 15)) * 8);
    *(bf16x8*)(w2t_hi + off) = hv;
    *(bf16x8*)(w2t_lo + off) = lv;
    sred[wid][lane] = sk;
    __syncthreads();
    if (wid == 0)
        atomicAdd(&S[lane], sred[0][lane] + sred[1][lane] + sred[2][lane] + sred[3][lane]);
}

// ---------------------------------------------------------------- k3: MFMA GEMM, m97 recipe (round-8, verified; kept).
// partials[ch][k][c] = sum_{l in chunk} w2[l][k] * x[c][l]
__global__ __launch_bounds__(256) void k3_mfma(const ushort* __restrict__ w2t_hi,
                                               const ushort* __restrict__ w2t_lo,
                                               const float* __restrict__ x,
                                               float* __restrict__ partials) {
    __shared__ ushort wa[2][8][512];    // 16 KB: A chunks [buf][plane*4+kg][lane*8]
    __shared__ float  xb[2][128][32];   // 32 KB: B tile [buf][c][l] (source-swizzled)
    int chunk = blockIdx.x;             // 0..191
    int c0 = blockIdx.y * 128;          // 0..3
    int l0 = chunk * CHUNKL;
    int lsbase = chunk * (CHUNKL / 32); // first 32-l step index
    int t = threadIdx.x, lane = t & 63, wid = t >> 6;
    int m = lane & 15, quad = lane >> 4;

    f32x4 acc[4][2];
#pragma unroll
    for (int kg = 0; kg < 4; ++kg)
#pragma unroll
        for (int cg = 0; cg < 2; ++cg) acc[kg][cg] = (f32x4){0.f, 0.f, 0.f, 0.f};

    // B staging geometry: lane rowg = lane>>3, phys granule g = lane&7; source l-granule = g^rowg.
    int rowg = lane >> 3, gph = lane & 7;
    int swzl = ((gph ^ rowg) * 4);

    // ---- prologue: stage step 0 into buf 0 ----
#pragma unroll
    for (int q = 0; q < 2; ++q) {
        int ch = 2 * wid + q;          // 0..7: plane = ch>>2, kg = ch&3
        const ushort* src = (ch < 4 ? w2t_hi : w2t_lo) + (size_t)(((lsbase * 4 + (ch & 3)) * 64 + lane) * 8);
        gl16(src, &wa[0][ch][(size_t)lane * 8]);
    }
#pragma unroll
    for (int i = 0; i < 4; ++i) {
        int row = wid * 32 + 8 * i + rowg;
        gl16(x + (size_t)(c0 + row) * LL + l0 + swzl, &xb[0][wid * 32 + 8 * i][0]);
    }

    int cur = 0;
#pragma unroll
    for (int st = 0; st < CHUNKL / 32; ++st) {
        __syncthreads();   // drains vmcnt: buf[cur] staged; prev reads of buf[cur^1] done
        if (st < CHUNKL / 32 - 1) {
#pragma unroll
            for (int q = 0; q < 2; ++q) {
                int ch = 2 * wid + q;
                const ushort* src = (ch < 4 ? w2t_hi : w2t_lo) +
                                    (size_t)((((lsbase + st + 1) * 4 + (ch & 3)) * 64 + lane) * 8);
                gl16(src, &wa[cur ^ 1][ch][(size_t)lane * 8]);
            }
#pragma unroll
            for (int i = 0; i < 4; ++i) {
                int row = wid * 32 + 8 * i + rowg;
                gl16(x + (size_t)(c0 + row) * LL + l0 + (st + 1) * 32 + swzl,
                     &xb[cur ^ 1][wid * 32 + 8 * i][0]);
            }
        }
        // ---- A frags: 8 ds_read_b128, conflict-free (2 lanes/bank) ----
        bf16x8 Ah[4], Al[4];
#pragma unroll
        for (int kg = 0; kg < 4; ++kg) {
            Ah[kg] = *(const bf16x8*)&wa[cur][kg    ][(size_t)lane * 8];
            Al[kg] = *(const bf16x8*)&wa[cur][4 + kg][(size_t)lane * 8];
        }
        // ---- B frags: 2x ds_read_b128 per cg at swizzled granules + in-register split ----
        bf16x8 Bh[2], Bl[2];
#pragma unroll
        for (int cg = 0; cg < 2; ++cg) {
            int crow = wid * 32 + cg * 16 + m;
            const float* xr = &xb[cur][crow][0];
            float4 v0 = *(const float4*)(xr + (((quad * 2    ) ^ (m & 7)) * 4));
            float4 v1 = *(const float4*)(xr + (((quad * 2 + 1) ^ (m & 7)) * 4));
            float vv[8] = {v0.x, v0.y, v0.z, v0.w, v1.x, v1.y, v1.z, v1.w};
#pragma unroll
            for (int j = 0; j < 8; ++j) {
                ushort h, lo;
                split2(vv[j], h, lo);
                Bh[cg][j] = (short)h; Bl[cg][j] = (short)lo;
            }
        }
        // ---- 3-term MFMA ----
#pragma unroll
        for (int cg = 0; cg < 2; ++cg)
#pragma unroll
            for (int kg = 0; kg < 4; ++kg) {
                acc[kg][cg] = __builtin_amdgcn_mfma_f32_16x16x32_bf16(Ah[kg], Bh[cg], acc[kg][cg], 0, 0, 0);
                acc[kg][cg] = __builtin_amdgcn_mfma_f32_16x16x32_bf16(Ah[kg], Bl[cg], acc[kg][cg], 0, 0, 0);
                acc[kg][cg] = __builtin_amdgcn_mfma_f32_16x16x32_bf16(Al[kg], Bh[cg], acc[kg][cg], 0, 0, 0);
            }
        cur ^= 1;
    }
    // ---- store: D row = kg*16 + quad*4 + r, col = c0 + wid*32 + cg*16 + m ----
    float* pp = partials + (size_t)chunk * KK * CC;
#pragma unroll
    for (int kg = 0; kg < 4; ++kg)
#pragma unroll
        for (int cg = 0; cg < 2; ++cg) {
            int cout = c0 + wid * 32 + cg * 16 + m;
#pragma unroll
            for (int r = 0; r < 4; ++r) {
                int kout = kg * 16 + quad * 4 + r;
                pp[(size_t)kout * CC + cout] = acc[kg][cg][r];
            }
        }
}

// ---------------------------------------------------------------- k4a: reduce partials -> vlad, rowsq atomic
__global__ __launch_bounds__(512) void k4a_reduce(const float* __restrict__ partials,
                                                  const float* __restrict__ S,
                                                  const float* __restrict__ cent,
                                                  float* __restrict__ vlad,
                                                  float* __restrict__ rowsq) {
    __shared__ float red[512];
    int k = blockIdx.x;
    int ci = threadIdx.x & 127;
    int c = blockIdx.y * 128 + ci;
    int q = threadIdx.x >> 7;                       // 0..3
    const float* pk = partials + (size_t)q * (NCHUNK / 4) * KK * CC + (size_t)k * CC + c;
    float s0 = 0.f, s1 = 0.f, s2 = 0.f, s3 = 0.f;
    for (int ch = 0; ch < NCHUNK / 4; ch += 4) {
        s0 += pk[(size_t)(ch + 0) * KK * CC];
        s1 += pk[(size_t)(ch + 1) * KK * CC];
        s2 += pk[(size_t)(ch + 2) * KK * CC];
        s3 += pk[(size_t)(ch + 3) * KK * CC];
    }
    red[threadIdx.x] = (s0 + s1) + (s2 + s3);
    __syncthreads();
    float vsq = 0.f;
    if (q == 0) {
        float v = red[ci] + red[ci + 128] + red[ci + 256] + red[ci + 384];
        v -= S[k] * cent[k * CC + c];
        vlad[k * CC + c] = v;
        vsq = v * v;
    }
    __syncthreads();
    red[threadIdx.x] = vsq;
    __syncthreads();
    for (int off = 256; off > 0; off >>= 1) {
        if (threadIdx.x < off) red[threadIdx.x] += red[threadIdx.x + off];
        __syncthreads();
    }
    if (threadIdx.x == 0) atomicAdd(&rowsq[k], red[0]);
}

// ---------------------------------------------------------------- k4c: out = vlad * rn[k], rn computed inline from rowsq
__global__ __launch_bounds__(256) void k4c_finish(const float* __restrict__ vlad,
                                                  const float* __restrict__ rowsq,
                                                  float* __restrict__ out) {
    __shared__ float rns[64];
    int t = threadIdx.x;
    if (t < 64) {
        float tot = rowsq[t];
        float r = 1.0f / fmaxf(sqrtf(tot), EPSF);
        float contrib = tot * r * r;
#pragma unroll
        for (int off = 32; off; off >>= 1) contrib += __shfl_xor(contrib, off, 64);
        float ginv = 1.0f / fmaxf(sqrtf(contrib), EPSF);
        rns[t] = r * ginv;
    }
    __syncthreads();
    int idx4 = blockIdx.x * 256 + t;               // 8192 float4s
    int k = idx4 >> 7;
    float s = rns[k];
    float4 v = ((const float4*)vlad)[idx4];
    v.x *= s; v.y *= s; v.z *= s; v.w *= s;
    ((float4*)out)[idx4] = v;
}

// ----------------------------------------------------------------
extern "C" void kernel_launch(void* const* d_in, const int* in_sizes, int n_in,
                              void* d_out, int out_size, void* d_ws, size_t ws_size,
                              hipStream_t stream) {
    const float* x      = (const float*)d_in[0];   // (512,192,192)
    const float* conv_w = (const float*)d_in[1];   // (64,512)
    const float* cent   = (const float*)d_in[2];   // (64,512)
    float* out = (float*)d_out;                    // 32768 fp32

    float* ws    = (float*)d_ws;
    ushort* Whi  = (ushort*)ws;                     // 32768 ushorts (fragment-ordered)
    ushort* Wmid = Whi + 32768;
    ushort* Wlo  = Wmid + 32768;                    // 3 x 64KB = 49152 floats total
    float* soft  = ws + 49152;                      // KK*LL
    float* invn  = soft + (size_t)KK * LL;          // 36864
    float* S     = invn + LL;                       // 64
    float* rowsq = S + KK;                          // 64  (S..rowsq contiguous 128 floats)
    float* vlad  = rowsq + KK;                      // 32768
    ull*   keep  = (ull*)(vlad + 32768);            // LL u64
    ushort* w2t_hi = (ushort*)(keep + LL);          // LL*KK ushorts (4.7 MB), fragment-ordered
    ushort* w2t_lo = w2t_hi + (size_t)LL * KK;      // LL*KK ushorts
    float* partials = (float*)(w2t_lo + (size_t)LL * KK);  // NCHUNK*KK*CC floats (25.2 MB)

    k0_prep<<<(KK * CC) / 256, 256, 0, stream>>>(conv_w, Whi, Wmid, Wlo, S);
    k1_logits<<<LL / 64, 256, 0, stream>>>(x, Whi, Wmid, Wlo, soft, invn, keep);
    k2_weight<<<LL / 32, 256, 0, stream>>>(soft, keep, invn, S, w2t_hi, w2t_lo);
    k3_mfma<<<dim3(NCHUNK, 4), 256, 0, stream>>>(w2t_hi, w2t_lo, x, partials);
    k4a_reduce<<<dim3(KK, 4), 512, 0, stream>>>(partials, S, cent, vlad, rowsq);
    k4c_finish<<<(KK * CC / 4) / 256, 256, 0, stream>>>(vlad, rowsq, out);
}

// Round 11
// 188.276 us; speedup vs baseline: 1.0774x; 1.0412x over previous
//
#include <hip/hip_runtime.h>

#define HH 192
#define WW 192
#define LL (HH * WW)   // 36864
#define CC 512
#define KK 64
#define EPSF 1e-12f
typedef unsigned long long ull;
typedef unsigned int uint;
typedef unsigned short ushort;

// k3 decomposition
#define NCHUNK 192
#define CHUNKL (LL / NCHUNK)   // 192

typedef short bf16x8 __attribute__((ext_vector_type(8)));
typedef float f32x4 __attribute__((ext_vector_type(4)));

// ---------------------------------------------------------------- async global->LDS, 16B per lane
__device__ __forceinline__ void gl16(const void* g, void* l) {
    __builtin_amdgcn_global_load_lds((const __attribute__((address_space(1))) void*)g,
                                     (__attribute__((address_space(3))) void*)l, 16, 0, 0);
}

// ---------------------------------------------------------------- fp32 -> 3-way bf16 split (hi/mid/lo, truncation; exact residuals)
__device__ inline void split3(float v, ushort& h, ushort& md, ushort& lo) {
    uint b  = __float_as_uint(v);
    uint hb = b & 0xFFFF0000u;
    float r1 = v - __uint_as_float(hb);          // exact
    uint mb = __float_as_uint(r1) & 0xFFFF0000u;
    float r2 = r1 - __uint_as_float(mb);         // exact
    uint lb = __float_as_uint(r2) & 0xFFFF0000u;
    h = (ushort)(hb >> 16); md = (ushort)(mb >> 16); lo = (ushort)(lb >> 16);
}

// ---------------------------------------------------------------- fp32 -> 2-way bf16 split (hi + residual lo)
__device__ inline void split2(float v, ushort& h, ushort& lo) {
    uint b  = __float_as_uint(v);
    uint hb = b & 0xFFFF0000u;
    float r = v - __uint_as_float(hb);           // exact
    h = (ushort)(hb >> 16); lo = (ushort)(__float_as_uint(r) >> 16);
}

// ---------------------------------------------------------------- k0: pre-split conv_w into fragment-ordered bf16 hi/mid/lo arrays.
// Fragment order: element W[kg*16+m][s*32 + quad*8 + j] -> ushort index ((s*4+kg)*64 + quad*16 + m)*8 + j
// so the W-slice for step s, kg is a contiguous 1KB block (64 lanes x 16B) -> one gl16.
__global__ __launch_bounds__(256) void k0_prep(const float* __restrict__ w,
                                               ushort* __restrict__ Whi,
                                               ushort* __restrict__ Wmid,
                                               ushort* __restrict__ Wlo,
                                               float* __restrict__ Szero) {
    int idx = blockIdx.x * 256 + threadIdx.x;   // 32768 = KK*CC
    int k = idx >> 9;
    int c = idx & 511;
    int s = c >> 5, w32 = c & 31, quad = w32 >> 3, j = w32 & 7;
    int kg = k >> 4, m = k & 15;
    int dst = (((s * 4 + kg) * 4 + quad) * 16 + m) * 8 + j;
    float v = w[idx];
    ushort h, md, lo;
    split3(v, h, md, lo);
    Whi[dst] = h; Wmid[dst] = md; Wlo[dst] = lo;
    if (blockIdx.x == 0 && threadIdx.x < 128) Szero[threadIdx.x] = 0.f;  // S[64]+rowsq[64]
}

// ---------------------------------------------------------------- k1: MFMA logits GEMM + fused norm/softmax/top2.
// v6 (rounds 7/8, best measured ~31 us; total 187.6): FULL m97 recipe — both operands staged
// via global_load_lds, fragments via ds_read_b128; double-buffered, one __syncthreads per
// 32-c step. LOCKED: six structural alternatives measured worse or neutral —
//  direct-global A-frags (46-48us, compiler serializes load->MFMA at L2 latency; VGPR=56/68
//  proves no batching), 2-wave/1152-block small barrier domains (48us), coalesced-LDS x with
//  direct A (46us), 4-wave ping-pong + sched_barrier (48us), triple-buffer + counted
//  vmcnt(5) + raw s_barrier (~39us: I-cache/occupancy cost exceeded pipeline gain).
// 6-term triple-bf16 MFMA => ~2^-24 rel err (fp32-equivalent) => top-2 SET selection stable.
__global__ __launch_bounds__(256) void k1_logits(const float* __restrict__ x,
                                                 const ushort* __restrict__ Whi,
                                                 const ushort* __restrict__ Wmid,
                                                 const ushort* __restrict__ Wlo,
                                                 float* __restrict__ soft,
                                                 float* __restrict__ invn,
                                                 ull* __restrict__ keep) {
    __shared__ ushort wl[2][12][512];   // 24 KB: W chunks [buf][plane*4+kg][lane*8]
    __shared__ float xs[2][32][64];     // 16 KB: x tile [buf][c-row][px]
    int t = threadIdx.x, lane = t & 63, wid = t >> 6;   // wid 0..3 = px-group
    int m = lane & 15, quad = lane >> 4;
    int pb = blockIdx.x * 64;

    f32x4 acc[4];
#pragma unroll
    for (int kg = 0; kg < 4; ++kg) acc[kg] = (f32x4){0.f, 0.f, 0.f, 0.f};
    float ss = 0.f;

    const ushort* Wp[3] = {Whi, Wmid, Wlo};
    // wave w stages x rows [4w,4w+4) and [16+4w,16+4w+4) of the 32-row step tile
    const float* gbase = x + (size_t)(4 * wid + quad) * LL + pb + m * 4;

    // ---- prologue: stage step 0 into buf 0 ----
    gl16(gbase, &xs[0][4 * wid][0]);
    gl16(gbase + (size_t)16 * LL, &xs[0][16 + 4 * wid][0]);
#pragma unroll
    for (int q = 0; q < 3; ++q) {
        int ch = 3 * wid + q;                  // 0..11: plane = ch>>2, kg = ch&3
        gl16(Wp[ch >> 2] + (size_t)(((0 * 4 + (ch & 3)) * 64 + lane) * 8), &wl[0][ch][(size_t)lane * 8]);
    }

    int cur = 0;
#pragma unroll
    for (int s = 0; s < 16; ++s) {
        __syncthreads();   // drains vmcnt: buf[cur] staged; prev reads of buf[cur^1] done
        if (s < 15) {
            const float* g = gbase + (size_t)(s + 1) * 32 * LL;
            gl16(g, &xs[cur ^ 1][4 * wid][0]);
            gl16(g + (size_t)16 * LL, &xs[cur ^ 1][16 + 4 * wid][0]);
#pragma unroll
            for (int q = 0; q < 3; ++q) {
                int ch = 3 * wid + q;
                gl16(Wp[ch >> 2] + (size_t)((((s + 1) * 4 + (ch & 3)) * 64 + lane) * 8),
                     &wl[cur ^ 1][ch][(size_t)lane * 8]);
            }
        }
        // ---- B frag from LDS: lane (m,quad) reads x[quad*8+j][wid*16+m] ----
        float xv[8];
#pragma unroll
        for (int j = 0; j < 8; ++j) xv[j] = xs[cur][quad * 8 + j][wid * 16 + m];
        bf16x8 Bh, Bm, Bl;
#pragma unroll
        for (int j = 0; j < 8; ++j) {
            float v = xv[j];
            ss = fmaf(v, v, ss);
            ushort h, md, lo;
            split3(v, h, md, lo);
            Bh[j] = (short)h; Bm[j] = (short)md; Bl[j] = (short)lo;
        }
        // ---- per kg: 3 ds_read_b128 A-frags + 6-term MFMA (<=3 A-frags live) ----
#pragma unroll
        for (int kg = 0; kg < 4; ++kg) {
            bf16x8 Ah = *(const bf16x8*)&wl[cur][kg    ][(size_t)lane * 8];
            bf16x8 Am = *(const bf16x8*)&wl[cur][4 + kg][(size_t)lane * 8];
            bf16x8 Al = *(const bf16x8*)&wl[cur][8 + kg][(size_t)lane * 8];
            f32x4 a = acc[kg];
            a = __builtin_amdgcn_mfma_f32_16x16x32_bf16(Ah, Bh, a, 0, 0, 0);
            a = __builtin_amdgcn_mfma_f32_16x16x32_bf16(Ah, Bm, a, 0, 0, 0);
            a = __builtin_amdgcn_mfma_f32_16x16x32_bf16(Am, Bh, a, 0, 0, 0);
            a = __builtin_amdgcn_mfma_f32_16x16x32_bf16(Ah, Bl, a, 0, 0, 0);
            a = __builtin_amdgcn_mfma_f32_16x16x32_bf16(Al, Bh, a, 0, 0, 0);
            a = __builtin_amdgcn_mfma_f32_16x16x32_bf16(Am, Bm, a, 0, 0, 0);
            acc[kg] = a;
        }
        cur ^= 1;
    }

    // ---- epilogue: wave-local (each wave owns its 16 px, full c contracted) ----
    ss += __shfl_xor(ss, 16);
    ss += __shfl_xor(ss, 32);
    float iv = 1.0f / fmaxf(sqrtf(ss), EPSF);
    int px = pb + wid * 16 + m;
    if (quad == 0) invn[px] = iv;

    float lg[16];
    float M1 = -3.0e38f, M2 = -3.0e38f; int I1 = 0, I2 = 0;
#pragma unroll
    for (int kg = 0; kg < 4; ++kg)
#pragma unroll
        for (int r = 0; r < 4; ++r) {
            float v = acc[kg][r] * iv;
            lg[kg * 4 + r] = v;
            int kk = kg * 16 + quad * 4 + r;
            if (v > M1)      { M2 = M1; I2 = I1; M1 = v; I1 = kk; }
            else if (v > M2) { M2 = v; I2 = kk; }
        }
    // cross-quad butterfly merge of (top1, top2), ties -> lower index
#pragma unroll
    for (int st = 0; st < 2; ++st) {
        int d = 16 << st;
        float a1 = __shfl_xor(M1, d); int b1 = __shfl_xor(I1, d);
        float a2 = __shfl_xor(M2, d); int b2 = __shfl_xor(I2, d);
        if (a1 > M1 || (a1 == M1 && b1 < I1)) { M2 = M1; I2 = I1; M1 = a1; I1 = b1; }
        else if (a1 > M2 || (a1 == M2 && b1 < I2)) { M2 = a1; I2 = b1; }
        if (a2 > M1 || (a2 == M1 && b2 < I1)) { M2 = M1; I2 = I1; M1 = a2; I1 = b2; }
        else if (a2 > M2 || (a2 == M2 && b2 < I2)) { M2 = a2; I2 = b2; }
    }

    float es = 0.f;
#pragma unroll
    for (int q = 0; q < 16; ++q) { float e = __expf(lg[q] - M1); lg[q] = e; es += e; }
    es += __shfl_xor(es, 16);
    es += __shfl_xor(es, 32);
    float rs = 1.0f / es;

    float4* sp = (float4*)(soft + (size_t)px * KK + quad * 4);
#pragma unroll
    for (int kg = 0; kg < 4; ++kg) {
        float4 o;
        o.x = lg[kg * 4 + 0] * rs; o.y = lg[kg * 4 + 1] * rs;
        o.z = lg[kg * 4 + 2] * rs; o.w = lg[kg * 4 + 3] * rs;
        sp[kg * 4] = o;     // soft[px*64 + kg*16 + quad*4 .. +3]
    }
    if (quad == 0) keep[px] = (1ull << I1) | (1ull << I2);
}

// ---------------------------------------------------------------- k2: weight = soft*cnt*border^4*invn[l]; S[k] += unscaled.
// Emits w2^T pre-split hi/lo bf16 planes in k3's A-fragment order; one 16B store per plane.
__global__ __launch_bounds__(256) void k2_weight(const float* __restrict__ soft,
                                                 const ull* __restrict__ keep,
                                                 const float* __restrict__ invn,
                                                 float* __restrict__ S,
                                                 ushort* __restrict__ w2t_hi,
                                                 ushort* __restrict__ w2t_lo) {
    __shared__ float sred[4][64];
    int t = threadIdx.x, lane = t & 63, wid = t >> 6;
    int l0 = blockIdx.x * 32 + wid * 8;
    float sk = 0.f;
    bf16x8 hv, lv;
#pragma unroll
    for (int p = 0; p < 8; ++p) {
        int l = l0 + p;                           // wave-uniform
        int i = l / WW, j = l % WW;
        int m = min(min(i, HH - 1 - i), min(j, WW - 1 - j));
        float bm = (float)m; bm *= bm; bm *= bm;  // m^4
        int cnt = 0;
#pragma unroll
        for (int di = -1; di <= 1; ++di) {
            int ii = i + di;
            if (ii < 0 || ii >= HH) continue;
#pragma unroll
            for (int dj = -1; dj <= 1; ++dj) {
                int jj = j + dj;
                if (jj < 0 || jj >= WW) continue;
                ull nb = keep[ii * WW + jj];      // uniform -> s_load
                cnt += (int)((nb >> lane) & 1ull);
            }
        }
        float v = soft[(size_t)l * KK + lane];    // coalesced 256B
        float u = v * (float)cnt * bm;            // unscaled weight
        sk += u;
        float w2v = u * invn[l];
        ushort h, lo;
        split2(w2v, h, lo);
        hv[p] = (short)h; lv[p] = (short)lo;
    }
    size_t off = (size_t)((((l0 >> 5) * 4 + (lane >> 4)) * 64 + ((l0 >> 3) & 3) * 16 + (lane & 15)) * 8);
    *(bf16x8*)(w2t_hi + off) = hv;
    *(bf16x8*)(w2t_lo + off) = lv;
    sred[wid][lane] = sk;
    __syncthreads();
    if (wid == 0)
        atomicAdd(&S[lane], sred[0][lane] + sred[1][lane] + sred[2][lane] + sred[3][lane]);
}

// ---------------------------------------------------------------- k3: MFMA GEMM, m97 recipe (round-8, best-verified; kept).
// partials[ch][k][c] = sum_{l in chunk} w2[l][k] * x[c][l]
// A = w2t hi/lo frag-slices via gl16; B = x[128c][32l] fp32 via gl16 with XOR-swizzled
// SOURCE addresses (G21/m173: linear LDS dest + pre-swizzled global src + swizzled
// ds_read_b128). Double-buffered, one __syncthreads per 32-l step.
__global__ __launch_bounds__(256) void k3_mfma(const ushort* __restrict__ w2t_hi,
                                               const ushort* __restrict__ w2t_lo,
                                               const float* __restrict__ x,
                                               float* __restrict__ partials) {
    __shared__ ushort wa[2][8][512];    // 16 KB: A chunks [buf][plane*4+kg][lane*8]
    __shared__ float  xb[2][128][32];   // 32 KB: B tile [buf][c][l] (source-swizzled)
    int chunk = blockIdx.x;             // 0..191
    int c0 = blockIdx.y * 128;          // 0..3
    int l0 = chunk * CHUNKL;
    int lsbase = chunk * (CHUNKL / 32); // first 32-l step index
    int t = threadIdx.x, lane = t & 63, wid = t >> 6;
    int m = lane & 15, quad = lane >> 4;

    f32x4 acc[4][2];
#pragma unroll
    for (int kg = 0; kg < 4; ++kg)
#pragma unroll
        for (int cg = 0; cg < 2; ++cg) acc[kg][cg] = (f32x4){0.f, 0.f, 0.f, 0.f};

    // B staging geometry: lane rowg = lane>>3, phys granule g = lane&7; source l-granule = g^rowg.
    int rowg = lane >> 3, gph = lane & 7;
    int swzl = ((gph ^ rowg) * 4);

    // ---- prologue: stage step 0 into buf 0 ----
#pragma unroll
    for (int q = 0; q < 2; ++q) {
        int ch = 2 * wid + q;          // 0..7: plane = ch>>2, kg = ch&3
        const ushort* src = (ch < 4 ? w2t_hi : w2t_lo) + (size_t)(((lsbase * 4 + (ch & 3)) * 64 + lane) * 8);
        gl16(src, &wa[0][ch][(size_t)lane * 8]);
    }
#pragma unroll
    for (int i = 0; i < 4; ++i) {
        int row = wid * 32 + 8 * i + rowg;
        gl16(x + (size_t)(c0 + row) * LL + l0 + swzl, &xb[0][wid * 32 + 8 * i][0]);
    }

    int cur = 0;
#pragma unroll
    for (int st = 0; st < CHUNKL / 32; ++st) {
        __syncthreads();   // drains vmcnt: buf[cur] staged; prev reads of buf[cur^1] done
        if (st < CHUNKL / 32 - 1) {
#pragma unroll
            for (int q = 0; q < 2; ++q) {
                int ch = 2 * wid + q;
                const ushort* src = (ch < 4 ? w2t_hi : w2t_lo) +
                                    (size_t)((((lsbase + st + 1) * 4 + (ch & 3)) * 64 + lane) * 8);
                gl16(src, &wa[cur ^ 1][ch][(size_t)lane * 8]);
            }
#pragma unroll
            for (int i = 0; i < 4; ++i) {
                int row = wid * 32 + 8 * i + rowg;
                gl16(x + (size_t)(c0 + row) * LL + l0 + (st + 1) * 32 + swzl,
                     &xb[cur ^ 1][wid * 32 + 8 * i][0]);
            }
        }
        // ---- A frags: 8 ds_read_b128, conflict-free (2 lanes/bank) ----
        bf16x8 Ah[4], Al[4];
#pragma unroll
        for (int kg = 0; kg < 4; ++kg) {
            Ah[kg] = *(const bf16x8*)&wa[cur][kg    ][(size_t)lane * 8];
            Al[kg] = *(const bf16x8*)&wa[cur][4 + kg][(size_t)lane * 8];
        }
        // ---- B frags: 2x ds_read_b128 per cg at swizzled granules + in-register split ----
        bf16x8 Bh[2], Bl[2];
#pragma unroll
        for (int cg = 0; cg < 2; ++cg) {
            int crow = wid * 32 + cg * 16 + m;
            const float* xr = &xb[cur][crow][0];
            float4 v0 = *(const float4*)(xr + (((quad * 2    ) ^ (m & 7)) * 4));
            float4 v1 = *(const float4*)(xr + (((quad * 2 + 1) ^ (m & 7)) * 4));
            float vv[8] = {v0.x, v0.y, v0.z, v0.w, v1.x, v1.y, v1.z, v1.w};
#pragma unroll
            for (int j = 0; j < 8; ++j) {
                ushort h, lo;
                split2(vv[j], h, lo);
                Bh[cg][j] = (short)h; Bl[cg][j] = (short)lo;
            }
        }
        // ---- 3-term MFMA ----
#pragma unroll
        for (int cg = 0; cg < 2; ++cg)
#pragma unroll
            for (int kg = 0; kg < 4; ++kg) {
                acc[kg][cg] = __builtin_amdgcn_mfma_f32_16x16x32_bf16(Ah[kg], Bh[cg], acc[kg][cg], 0, 0, 0);
                acc[kg][cg] = __builtin_amdgcn_mfma_f32_16x16x32_bf16(Ah[kg], Bl[cg], acc[kg][cg], 0, 0, 0);
                acc[kg][cg] = __builtin_amdgcn_mfma_f32_16x16x32_bf16(Al[kg], Bh[cg], acc[kg][cg], 0, 0, 0);
            }
        cur ^= 1;
    }
    // ---- store: D row = kg*16 + quad*4 + r, col = c0 + wid*32 + cg*16 + m ----
    float* pp = partials + (size_t)chunk * KK * CC;
#pragma unroll
    for (int kg = 0; kg < 4; ++kg)
#pragma unroll
        for (int cg = 0; cg < 2; ++cg) {
            int cout = c0 + wid * 32 + cg * 16 + m;
#pragma unroll
            for (int r = 0; r < 4; ++r) {
                int kout = kg * 16 + quad * 4 + r;
                pp[(size_t)kout * CC + cout] = acc[kg][cg][r];
            }
        }
}

// ---------------------------------------------------------------- k4a: reduce partials -> vlad, rowsq atomic
__global__ __launch_bounds__(512) void k4a_reduce(const float* __restrict__ partials,
                                                  const float* __restrict__ S,
                                                  const float* __restrict__ cent,
                                                  float* __restrict__ vlad,
                                                  float* __restrict__ rowsq) {
    __shared__ float red[512];
    int k = blockIdx.x;
    int ci = threadIdx.x & 127;
    int c = blockIdx.y * 128 + ci;
    int q = threadIdx.x >> 7;                       // 0..3
    const float* pk = partials + (size_t)q * (NCHUNK / 4) * KK * CC + (size_t)k * CC + c;
    float s0 = 0.f, s1 = 0.f, s2 = 0.f, s3 = 0.f;
    for (int ch = 0; ch < NCHUNK / 4; ch += 4) {
        s0 += pk[(size_t)(ch + 0) * KK * CC];
        s1 += pk[(size_t)(ch + 1) * KK * CC];
        s2 += pk[(size_t)(ch + 2) * KK * CC];
        s3 += pk[(size_t)(ch + 3) * KK * CC];
    }
    red[threadIdx.x] = (s0 + s1) + (s2 + s3);
    __syncthreads();
    float vsq = 0.f;
    if (q == 0) {
        float v = red[ci] + red[ci + 128] + red[ci + 256] + red[ci + 384];
        v -= S[k] * cent[k * CC + c];
        vlad[k * CC + c] = v;
        vsq = v * v;
    }
    __syncthreads();
    red[threadIdx.x] = vsq;
    __syncthreads();
    for (int off = 256; off > 0; off >>= 1) {
        if (threadIdx.x < off) red[threadIdx.x] += red[threadIdx.x + off];
        __syncthreads();
    }
    if (threadIdx.x == 0) atomicAdd(&rowsq[k], red[0]);
}

// ---------------------------------------------------------------- k4c: out = vlad * rn[k], rn computed inline from rowsq
__global__ __launch_bounds__(256) void k4c_finish(const float* __restrict__ vlad,
                                                  const float* __restrict__ rowsq,
                                                  float* __restrict__ out) {
    __shared__ float rns[64];
    int t = threadIdx.x;
    if (t < 64) {
        float tot = rowsq[t];
        float r = 1.0f / fmaxf(sqrtf(tot), EPSF);
        float contrib = tot * r * r;
#pragma unroll
        for (int off = 32; off; off >>= 1) contrib += __shfl_xor(contrib, off, 64);
        float ginv = 1.0f / fmaxf(sqrtf(contrib), EPSF);
        rns[t] = r * ginv;
    }
    __syncthreads();
    int idx4 = blockIdx.x * 256 + t;               // 8192 float4s
    int k = idx4 >> 7;
    float s = rns[k];
    float4 v = ((const float4*)vlad)[idx4];
    v.x *= s; v.y *= s; v.z *= s; v.w *= s;
    ((float4*)out)[idx4] = v;
}

// ----------------------------------------------------------------
extern "C" void kernel_launch(void* const* d_in, const int* in_sizes, int n_in,
                              void* d_out, int out_size, void* d_ws, size_t ws_size,
                              hipStream_t stream) {
    const float* x      = (const float*)d_in[0];   // (512,192,192)
    const float* conv_w = (const float*)d_in[1];   // (64,512)
    const float* cent   = (const float*)d_in[2];   // (64,512)
    float* out = (float*)d_out;                    // 32768 fp32

    float* ws    = (float*)d_ws;
    ushort* Whi  = (ushort*)ws;                     // 32768 ushorts (fragment-ordered)
    ushort* Wmid = Whi + 32768;
    ushort* Wlo  = Wmid + 32768;                    // 3 x 64KB = 49152 floats total
    float* soft  = ws + 49152;                      // KK*LL
    float* invn  = soft + (size_t)KK * LL;          // 36864
    float* S     = invn + LL;                       // 64
    float* rowsq = S + KK;                          // 64  (S..rowsq contiguous 128 floats)
    float* vlad  = rowsq + KK;                      // 32768
    ull*   keep  = (ull*)(vlad + 32768);            // LL u64
    ushort* w2t_hi = (ushort*)(keep + LL);          // LL*KK ushorts (4.7 MB), fragment-ordered
    ushort* w2t_lo = w2t_hi + (size_t)LL * KK;      // LL*KK ushorts
    float* partials = (float*)(w2t_lo + (size_t)LL * KK);  // NCHUNK*KK*CC floats (25.2 MB)

    k0_prep<<<(KK * CC) / 256, 256, 0, stream>>>(conv_w, Whi, Wmid, Wlo, S);
    k1_logits<<<LL / 64, 256, 0, stream>>>(x, Whi, Wmid, Wlo, soft, invn, keep);
    k2_weight<<<LL / 32, 256, 0, stream>>>(soft, keep, invn, S, w2t_hi, w2t_lo);
    k3_mfma<<<dim3(NCHUNK, 4), 256, 0, stream>>>(w2t_hi, w2t_lo, x, partials);
    k4a_reduce<<<dim3(KK, 4), 512, 0, stream>>>(partials, S, cent, vlad, rowsq);
    k4c_finish<<<(KK * CC / 4) / 256, 256, 0, stream>>>(vlad, rowsq, out);
}